// Round 1
// baseline (267.391 us; speedup 1.0000x reference)
//
#include <hip/hip_runtime.h>

// ToeplitzMemoryProjection (HiPPO LagT, alpha=0.5 bilinear).
//
// Math: with delta = 0.5*dt, c = 1 + 0.25*dt, g = (1-0.25*dt)/(1+0.25*dt),
// beta = dt*u/c, the per-step Toeplitz operator is (g*I - S)(I - g*S)^{-1}
// and the input term is beta*(I - g*S)^{-1} e0 (S = down-shift). Multiplying
// the scan step x_l = A_l x_{l-1} + B_l by (I - g_l S) (exact in the
// truncated lower-tri Toeplitz algebra used by the reference) gives:
//
//   x_l[i] = g_l*(x_l[i-1] + x_{l-1}[i]) - x_{l-1}[i-1] + beta_l*[i==0]
//
// i.e. an O(N) recurrence per step instead of an O(N^2) convolution.
// Implemented as a lane-skewed wavefront over the (l,i) grid:
//   - 1 block per channel (B*M = 256 channels), 256 threads (i = tid).
//   - thread i processes row l at tick T = l + i + wave*K extra skew;
//     intra-wave neighbor values via __shfl_up, cross-wave via LDS handoff
//     rings that are always >= 1 barrier-chunk old (K-tick chunks).
//   - outputs staged in per-wave LDS row rings, flushed as coalesced
//     64-lane (256 B) row-segment stores.

namespace {

constexpr int LLEN  = 1024;              // L
constexpr int NCHAN = 256;               // B*M
constexpr int NWAVE = 4;                 // waves per block (N = 256 lanes)
constexpr int KCH   = 16;                // ticks per chunk (barrier period)
constexpr int SKEW  = 64 + KCH;          // per-wave tick offset (80)
constexpr int RING  = 128;               // per-wave row ring depth (pow2)
constexpr int HOFF  = 64;                // handoff ring depth (pow2)
constexpr int LAST_T = (LLEN - 1) + 255 + (NWAVE - 1) * KCH;  // 1326
constexpr int NCHUNK = LAST_T / KCH + 1; // 83 -> covers T in [0, 1328)

constexpr int G_OFF = 0;
constexpr int B_OFF = LLEN;
constexpr int H_OFF = 2 * LLEN;
constexpr int R_OFF = 2 * LLEN + NWAVE * HOFF;
constexpr int LDS_FLOATS = R_OFF + NWAVE * RING * 64;
constexpr size_t LDS_BYTES = (size_t)LDS_FLOATS * sizeof(float);  // 140288 B

__global__ __launch_bounds__(256, 1)
void toeplitz_scan(const float* __restrict__ vin,   // inputs (L, 256)
                   const float* __restrict__ dtin,  // dt     (L, 256)
                   float* __restrict__ out)         // (L, 256, 256)
{
    extern __shared__ float lds[];
    float* g_arr = lds + G_OFF;   // [LLEN]
    float* b_arr = lds + B_OFF;   // [LLEN]
    float* hoff  = lds + H_OFF;   // [NWAVE][HOFF]
    float* ring  = lds + R_OFF;   // [NWAVE][RING][64]

    const int ch   = blockIdx.x;
    const int tid  = threadIdx.x;
    const int wave = tid >> 6;
    const int lane = tid & 63;

    // ---- precompute g[l], beta[l] for this channel ----
    #pragma unroll
    for (int k = 0; k < LLEN / 256; ++k) {
        const int l = tid + k * 256;
        const float d = dtin[l * NCHAN + ch];
        const float u = vin[l * NCHAN + ch];
        const float inv_c = 1.0f / (1.0f + 0.25f * d);  // IEEE-exact div
        g_arr[l] = (1.0f - 0.25f * d) * inv_c;
        b_arr[l] = d * u * inv_c;
    }
    __syncthreads();

    float* my_ring = ring + wave * (RING * 64);
    const float* lf_hoff = hoff + (wave > 0 ? (wave - 1) * HOFF : 0);
    float* my_hoff = hoff + wave * HOFF;

    const int t_off   = wave * SKEW + lane;   // row l = T - t_off
    const bool lane0  = (lane == 0);
    const bool lane63 = (lane == 63);
    const bool g0     = (tid == 0);
    const bool w0     = (wave == 0);

    float prev_own = 0.0f;   // x_{l-1}[i]
    float prev_left = 0.0f;  // x_{l-1}[i-1]
    int nf = 0;              // next row to flush (per wave)
    const int out_base = ch * 256 + wave * 64 + lane;  // + l * 65536

    for (int c = 0; c < NCHUNK; ++c) {
        const int T0 = c * KCH;
        #pragma unroll
        for (int s = 0; s < KCH; ++s) {
            const int l = T0 + s - t_off;
            const bool active = (l >= 0) & (l < LLEN);
            const int lc = min(max(l, 0), LLEN - 1);
            const float gg = g_arr[lc];
            // x_l[i-1]: intra-wave via shuffle, wave boundary via handoff ring
            float cur_left = __shfl_up(prev_own, 1);
            if (lane0) cur_left = w0 ? 0.0f : lf_hoff[l & (HOFF - 1)];
            float bv = 0.0f;
            if (g0 && active) bv = b_arr[lc];
            const float x = fmaf(gg, cur_left + prev_own, bv - prev_left);
            if (active) {
                my_ring[((l & (RING - 1)) << 6) + lane] = x;
                if (lane63) my_hoff[l & (HOFF - 1)] = x;
                prev_left = cur_left;
                prev_own  = x;
            }
        }
        __syncthreads();
        // flush rows this wave fully completed (lane 63 reached them)
        const int hi0 = T0 + KCH - wave * SKEW - 64;  // inclusive bound
        const int hi = min(hi0, LLEN - 1);
        for (; nf <= hi; ++nf) {
            const float v = my_ring[((nf & (RING - 1)) << 6) + lane];
            out[nf * (NCHAN * 256) + out_base] = v;
        }
    }
    // safety drain (should be empty: last chunk covers all rows)
    for (; nf < LLEN; ++nf) {
        const float v = my_ring[((nf & (RING - 1)) << 6) + lane];
        out[nf * (NCHAN * 256) + out_base] = v;
    }
}

} // namespace

extern "C" void kernel_launch(void* const* d_in, const int* in_sizes, int n_in,
                              void* d_out, int out_size, void* d_ws, size_t ws_size,
                              hipStream_t stream) {
    (void)in_sizes; (void)n_in; (void)d_ws; (void)ws_size; (void)out_size;
    const float* vin  = (const float*)d_in[0];   // "inputs"
    const float* dtin = (const float*)d_in[1];   // "dt"
    float* out = (float*)d_out;

    // LDS: 140288 B/block (> 64 KiB default) -> opt in. Host-side attribute
    // set, not a stream op: graph-capture safe; deterministic every call.
    (void)hipFuncSetAttribute(reinterpret_cast<const void*>(toeplitz_scan),
                              hipFuncAttributeMaxDynamicSharedMemorySize,
                              (int)LDS_BYTES);

    toeplitz_scan<<<NCHAN, 256, LDS_BYTES, stream>>>(vin, dtin, out);
}

// Round 2
// 89.753 us; speedup vs baseline: 2.9792x; 2.9792x over previous
//
#include <hip/hip_runtime.h>

// ToeplitzMemoryProjection (HiPPO LagT, alpha=0.5 bilinear).
//
// Math: with c = 1 + 0.25*dt, g = (1-0.25*dt)/c, beta = dt*u/c, the step
// operator is (g*I - S)(I - g*S)^{-1} (S = down-shift) and the input term is
// beta*(I - g*S)^{-1} e0. Multiplying the scan x_l = A_l x_{l-1} + B_l by
// (I - g_l S) (exact in the truncated lower-tri Toeplitz algebra) gives the
// O(N)-per-step recurrence
//
//   x_l[i] = g_l*(x_l[i-1] + x_{l-1}[i]) - x_{l-1}[i-1] + beta_l*[i==0]
//
// Lane-skewed wavefront: 1 block per channel (256 ch), 256 threads (col = tid),
// thread i handles row l at tick T = l + wave*SKEW + lane.
//   - x_l[i-1] via DPP wave_shr:1 (VALU-latency lane shift, lane0 -> 0)
//   - cross-wave handoff: lane0 reads left wave's ring column 63 directly
//     (written >= 1 barrier-chunk earlier; SKEW-63 = 17 > KCH = 16)
//   - ring slots are TICK-indexed (slot = t & 127, wave-uniform) so the ring
//     write is a single ds_write with immediate offset (T0&127 <= 112, so a
//     16-tick chunk never wraps mid-chunk)
//   - chunk-level uniform fast/masked/inactive classification: interior
//     chunks run with zero per-tick masking or clamping
//   - completed rows flushed as coalesced 256 B nontemporal row-segment stores

namespace {

constexpr int LLEN  = 1024;              // L
constexpr int NCHAN = 256;               // B*M
constexpr int NWAVE = 4;                 // waves per block (N = 256 cols)
constexpr int KCH   = 16;                // ticks per chunk (barrier period)
constexpr int SKEW  = 64 + KCH;          // per-wave tick offset (80); SKEW-63=17>KCH
constexpr int RINGT = 128;               // tick-indexed ring slots per wave (pow2)
constexpr int LAST_T = (LLEN - 1) + 255 + (NWAVE - 1) * KCH;  // 1326
constexpr int NCHUNK = LAST_T / KCH + 1; // 83

constexpr int G_OFF = 0;
constexpr int B_OFF = LLEN;
constexpr int R_OFF = 2 * LLEN;
constexpr int LDS_FLOATS = R_OFF + NWAVE * RINGT * 64;
constexpr size_t LDS_BYTES = (size_t)LDS_FLOATS * sizeof(float);  // 139264 B

__device__ __forceinline__ float dpp_wave_shr1(float v) {
    // v_mov_b32_dpp wave_shr:1 — lane i gets lane i-1's value, lane 0 gets `old`=0.
    return __int_as_float(__builtin_amdgcn_update_dpp(
        0, __float_as_int(v), 0x138 /*WAVE_SHR1*/, 0xF, 0xF, false));
}

// One 16-tick chunk of the wavefront recurrence.
// hb[s]: for W0 (wave 0) the beta values b_arr[T0+s] (used by lane 0);
//        for other waves the left wave's column-63 x values (used by lane 0).
template <bool W0, bool MASKED>
__device__ __forceinline__ void do_chunk(
    int T0, int base_l, int lane, bool lane0,
    const float* __restrict__ g_arr, const float (&hb)[KCH],
    float* __restrict__ my_ring, float& prev_own, float& prev_left)
{
    const int rb = ((T0 & (RINGT - 1)) << 6) + lane;  // never wraps mid-chunk
    #pragma unroll
    for (int s = 0; s < KCH; ++s) {
        const int l = base_l + s - lane;
        float gg;
        if (MASKED) {
            const int lc = min(max(l, 0), LLEN - 1);
            gg = g_arr[lc];
        } else {
            gg = g_arr[l];
        }
        float cl = dpp_wave_shr1(prev_own);
        const float sel = lane0 ? hb[s] : 0.0f;
        if (!W0) cl = cl + sel;                       // lane0: left wave handoff
        const float cterm = W0 ? (sel - prev_left)    // lane0: +beta
                               : (0.0f - prev_left);
        const float x = fmaf(gg, cl, fmaf(gg, prev_own, cterm));
        my_ring[rb + (s << 6)] = x;                   // garbage for OOB rows is
                                                      // never flushed: harmless
        if (MASKED) {
            const bool act = (l >= 0) & (l < LLEN);
            prev_left = act ? cl : prev_left;
            prev_own  = act ? x  : prev_own;
        } else {
            prev_left = cl;
            prev_own  = x;
        }
    }
}

__global__ __launch_bounds__(256, 1)
void toeplitz_scan(const float* __restrict__ vin,   // inputs (L, 256)
                   const float* __restrict__ dtin,  // dt     (L, 256)
                   float* __restrict__ out)         // (L, 256, 256)
{
    extern __shared__ float lds[];
    float* g_arr = lds + G_OFF;   // [LLEN]
    float* b_arr = lds + B_OFF;   // [LLEN]
    float* ring  = lds + R_OFF;   // [NWAVE][RINGT][64], tick-indexed slots

    const int ch   = blockIdx.x;
    const int tid  = threadIdx.x;
    const int wave = tid >> 6;
    const int lane = tid & 63;

    // ---- precompute g[l], beta[l] for this channel ----
    #pragma unroll
    for (int k = 0; k < LLEN / 256; ++k) {
        const int l = tid + k * 256;
        const float d = dtin[l * NCHAN + ch];
        const float u = vin[l * NCHAN + ch];
        const float inv_c = 1.0f / (1.0f + 0.25f * d);
        g_arr[l] = (1.0f - 0.25f * d) * inv_c;
        b_arr[l] = d * u * inv_c;
    }
    __syncthreads();

    float* my_ring = ring + wave * (RINGT * 64);
    const float* lf_ring = ring + (wave - 1) * (RINGT * 64);  // valid for wave>0

    const int wskew  = wave * SKEW;
    const bool w0    = (wave == 0);
    const bool lane0 = (lane == 0);

    float prev_own = 0.0f, prev_left = 0.0f;
    int nf = 0;                                   // next row to flush
    float* outp = out + (ch * 256 + wave * 64 + lane);  // +65536 per row

    for (int c = 0; c < NCHUNK; ++c) {
        const int T0 = c * KCH;
        const int base_l = T0 - wskew;            // lane0's row at s=0
        const bool any_act = (base_l >= -(KCH - 1)) && (base_l <= LLEN - 1 + 63);

        if (any_act) {
            const bool all_act = (base_l >= 63) && (base_l <= LLEN - KCH);
            float hb[KCH];
            if (w0) {
                if (all_act) {
                    #pragma unroll
                    for (int q = 0; q < KCH / 4; ++q) {
                        const float4 t =
                            *reinterpret_cast<const float4*>(&b_arr[T0 + 4 * q]);
                        hb[4*q+0] = t.x; hb[4*q+1] = t.y;
                        hb[4*q+2] = t.z; hb[4*q+3] = t.w;
                    }
                } else {
                    #pragma unroll
                    for (int s = 0; s < KCH; ++s)
                        hb[s] = b_arr[min(T0 + s, LLEN - 1)];
                }
                if (all_act)
                    do_chunk<true, false>(T0, base_l, lane, lane0, g_arr, hb,
                                          my_ring, prev_own, prev_left);
                else
                    do_chunk<true, true>(T0, base_l, lane, lane0, g_arr, hb,
                                         my_ring, prev_own, prev_left);
            } else {
                // left wave's lane-63 values: slot (T0+s-17) & 127, col 63.
                // Written >= 1 barrier ago (17 > KCH); broadcast reads.
                float hb2[KCH];
                #pragma unroll
                for (int s = 0; s < KCH; ++s) {
                    const int slot = (T0 + s - (SKEW - 63)) & (RINGT - 1);
                    hb2[s] = lf_ring[(slot << 6) + 63];
                }
                if (all_act)
                    do_chunk<false, false>(T0, base_l, lane, lane0, g_arr, hb2,
                                           my_ring, prev_own, prev_left);
                else
                    do_chunk<false, true>(T0, base_l, lane, lane0, g_arr, hb2,
                                          my_ring, prev_own, prev_left);
            }
        }

        // ---- flush rows whose lane-63 value landed by tick T0+KCH-1 ----
        {
            const int hi = min(base_l + KCH - 64, LLEN - 1);
            if (hi - nf == KCH - 1) {             // steady state: exactly KCH rows
                #pragma unroll
                for (int q = 0; q < KCH; ++q) {
                    const int slot = (nf + wskew + lane) & (RINGT - 1);
                    __builtin_nontemporal_store(my_ring[(slot << 6) + lane], outp);
                    outp += NCHAN * 256;
                    ++nf;
                }
            } else {
                for (; nf <= hi; ++nf) {
                    const int slot = (nf + wskew + lane) & (RINGT - 1);
                    __builtin_nontemporal_store(my_ring[(slot << 6) + lane], outp);
                    outp += NCHAN * 256;
                }
            }
        }
        __syncthreads();
    }

    // safety drain (normally empty)
    for (; nf < LLEN; ++nf) {
        const int slot = (nf + wskew + lane) & (RINGT - 1);
        __builtin_nontemporal_store(my_ring[(slot << 6) + lane], outp);
        outp += NCHAN * 256;
    }
}

} // namespace

extern "C" void kernel_launch(void* const* d_in, const int* in_sizes, int n_in,
                              void* d_out, int out_size, void* d_ws, size_t ws_size,
                              hipStream_t stream) {
    (void)in_sizes; (void)n_in; (void)d_ws; (void)ws_size; (void)out_size;
    const float* vin  = (const float*)d_in[0];   // "inputs"
    const float* dtin = (const float*)d_in[1];   // "dt"
    float* out = (float*)d_out;

    (void)hipFuncSetAttribute(reinterpret_cast<const void*>(toeplitz_scan),
                              hipFuncAttributeMaxDynamicSharedMemorySize,
                              (int)LDS_BYTES);

    toeplitz_scan<<<NCHAN, 256, LDS_BYTES, stream>>>(vin, dtin, out);
}

// Round 3
// 85.005 us; speedup vs baseline: 3.1456x; 1.0559x over previous
//
#include <hip/hip_runtime.h>

// ToeplitzMemoryProjection (HiPPO LagT, alpha=0.5 bilinear).
//
// Math: with c = 1 + 0.25*dt, g = (1-0.25*dt)/c, beta = dt*u/c, the step
// operator is (g*I - S)(I - g*S)^{-1} (S = down-shift) and the input term is
// beta*(I - g*S)^{-1} e0. Multiplying the scan x_l = A_l x_{l-1} + B_l by
// (I - g_l S) (exact in the truncated lower-tri Toeplitz algebra) gives the
// O(N)-per-step recurrence
//
//   x_l[i] = g_l*(x_l[i-1] + x_{l-1}[i]) - x_{l-1}[i-1] + beta_l*[i==0]
//
// Lane-skewed wavefront: 1 block per channel (256 ch), 256 threads (col = tid),
// thread i handles row l at tick T = l + wave*SKEW + lane.
//   - x_l[i-1] via DPP wave_shr:1 (VALU-latency lane shift, lane0 -> 0)
//   - cross-wave handoff: lane0 reads left wave's ring column 63 directly
//     (written >= 1 barrier-chunk earlier; SKEW-63 = 33 > KCH = 32 - 1)
//   - ring slots are TICK-indexed (slot = t & 127, wave-uniform): ring write is
//     one ds_write with immediate offset (T0&127 in {0,32,64,96}; a 32-tick
//     chunk never wraps mid-chunk)
//   - barriers are LDS-only: raw s_barrier + s_waitcnt lgkmcnt(0) (NO vmcnt
//     drain) so the nontemporal HBM store stream stays in flight across
//     chunks. The barrier only orders LDS ring handoffs; global stores need
//     no inter-wave ordering. sched_barrier(0) fences per methodology rule 18.
//   - completed rows flushed as coalesced 256 B nontemporal row-segment stores

namespace {

constexpr int LLEN  = 1024;              // L
constexpr int NCHAN = 256;               // B*M
constexpr int NWAVE = 4;                 // waves per block (N = 256 cols)
constexpr int KCH   = 32;                // ticks per chunk (barrier period)
constexpr int SKEW  = 64 + KCH;          // per-wave tick offset (96); SKEW-63=33>KCH-1
constexpr int RINGT = 128;               // tick-indexed ring slots per wave (pow2)
constexpr int LAST_T = (LLEN - 1) + 255 + (NWAVE - 1) * KCH;  // 1374
constexpr int NCHUNK = LAST_T / KCH + 1; // 43

constexpr int G_OFF = 0;
constexpr int B_OFF = LLEN;
constexpr int R_OFF = 2 * LLEN;
constexpr int LDS_FLOATS = R_OFF + NWAVE * RINGT * 64;
constexpr size_t LDS_BYTES = (size_t)LDS_FLOATS * sizeof(float);  // 139264 B

__device__ __forceinline__ float dpp_wave_shr1(float v) {
    // v_mov_b32_dpp wave_shr:1 — lane i gets lane i-1's value, lane 0 gets `old`=0.
    return __int_as_float(__builtin_amdgcn_update_dpp(
        0, __float_as_int(v), 0x138 /*WAVE_SHR1*/, 0xF, 0xF, false));
}

// LDS-only barrier: order ring ds_writes/ds_reads across waves WITHOUT
// draining the global store queue (vmcnt untouched).
__device__ __forceinline__ void lds_barrier() {
    __builtin_amdgcn_sched_barrier(0);
    asm volatile("s_waitcnt lgkmcnt(0)" ::: "memory");
    __builtin_amdgcn_s_barrier();
    __builtin_amdgcn_sched_barrier(0);
}

// One KCH-tick chunk of the wavefront recurrence.
// hb[s]: for W0 (wave 0) the beta values b_arr[T0+s] (used by lane 0);
//        for other waves the left wave's column-63 x values (used by lane 0).
template <bool W0, bool MASKED>
__device__ __forceinline__ void do_chunk(
    int T0, int base_l, int lane, bool lane0,
    const float* __restrict__ g_arr, const float (&hb)[KCH],
    float* __restrict__ my_ring, float& prev_own, float& prev_left)
{
    const int rb = ((T0 & (RINGT - 1)) << 6) + lane;  // never wraps mid-chunk
    #pragma unroll
    for (int s = 0; s < KCH; ++s) {
        const int l = base_l + s - lane;
        float gg;
        if (MASKED) {
            const int lc = min(max(l, 0), LLEN - 1);
            gg = g_arr[lc];
        } else {
            gg = g_arr[l];
        }
        float cl = dpp_wave_shr1(prev_own);
        const float sel = lane0 ? hb[s] : 0.0f;
        if (!W0) cl = cl + sel;                       // lane0: left wave handoff
        const float cterm = W0 ? (sel - prev_left)    // lane0: +beta
                               : (0.0f - prev_left);
        const float x = fmaf(gg, cl, fmaf(gg, prev_own, cterm));
        my_ring[rb + (s << 6)] = x;                   // garbage for OOB rows is
                                                      // never flushed: harmless
        if (MASKED) {
            const bool act = (l >= 0) & (l < LLEN);
            prev_left = act ? cl : prev_left;
            prev_own  = act ? x  : prev_own;
        } else {
            prev_left = cl;
            prev_own  = x;
        }
    }
}

__global__ __launch_bounds__(256, 1)
void toeplitz_scan(const float* __restrict__ vin,   // inputs (L, 256)
                   const float* __restrict__ dtin,  // dt     (L, 256)
                   float* __restrict__ out)         // (L, 256, 256)
{
    extern __shared__ float lds[];
    float* g_arr = lds + G_OFF;   // [LLEN]
    float* b_arr = lds + B_OFF;   // [LLEN]
    float* ring  = lds + R_OFF;   // [NWAVE][RINGT][64], tick-indexed slots

    const int ch   = blockIdx.x;
    const int tid  = threadIdx.x;
    const int wave = tid >> 6;
    const int lane = tid & 63;

    // ---- precompute g[l], beta[l] for this channel ----
    #pragma unroll
    for (int k = 0; k < LLEN / 256; ++k) {
        const int l = tid + k * 256;
        const float d = dtin[l * NCHAN + ch];
        const float u = vin[l * NCHAN + ch];
        const float inv_c = 1.0f / (1.0f + 0.25f * d);
        g_arr[l] = (1.0f - 0.25f * d) * inv_c;
        b_arr[l] = d * u * inv_c;
    }
    __syncthreads();

    float* my_ring = ring + wave * (RINGT * 64);
    const float* lf_ring = ring + (wave - 1) * (RINGT * 64);  // valid for wave>0

    const int wskew  = wave * SKEW;
    const bool w0    = (wave == 0);
    const bool lane0 = (lane == 0);

    float prev_own = 0.0f, prev_left = 0.0f;
    int nf = 0;                                   // next row to flush
    float* outp = out + (ch * 256 + wave * 64 + lane);  // +65536 per row

    for (int c = 0; c < NCHUNK; ++c) {
        const int T0 = c * KCH;
        const int base_l = T0 - wskew;            // lane0's row at s=0
        const bool any_act = (base_l >= -(KCH - 1)) && (base_l <= LLEN - 1 + 63);

        if (any_act) {
            const bool all_act = (base_l >= 63) && (base_l <= LLEN - KCH);
            float hb[KCH];
            if (w0) {
                if (all_act) {
                    #pragma unroll
                    for (int q = 0; q < KCH / 4; ++q) {
                        const float4 t =
                            *reinterpret_cast<const float4*>(&b_arr[T0 + 4 * q]);
                        hb[4*q+0] = t.x; hb[4*q+1] = t.y;
                        hb[4*q+2] = t.z; hb[4*q+3] = t.w;
                    }
                } else {
                    #pragma unroll
                    for (int s = 0; s < KCH; ++s)
                        hb[s] = b_arr[min(T0 + s, LLEN - 1)];
                }
                if (all_act)
                    do_chunk<true, false>(T0, base_l, lane, lane0, g_arr, hb,
                                          my_ring, prev_own, prev_left);
                else
                    do_chunk<true, true>(T0, base_l, lane, lane0, g_arr, hb,
                                         my_ring, prev_own, prev_left);
            } else {
                // left wave's lane-63 values: slot (T0+s-33) & 127, col 63.
                // Written >= 1 barrier-chunk ago (s-33 < 0 for s < KCH);
                // overwritten only at tick+128 (>= 3 chunks later). Broadcast.
                float hb2[KCH];
                #pragma unroll
                for (int s = 0; s < KCH; ++s) {
                    const int slot = (T0 + s - (SKEW - 63)) & (RINGT - 1);
                    hb2[s] = lf_ring[(slot << 6) + 63];
                }
                if (all_act)
                    do_chunk<false, false>(T0, base_l, lane, lane0, g_arr, hb2,
                                           my_ring, prev_own, prev_left);
                else
                    do_chunk<false, true>(T0, base_l, lane, lane0, g_arr, hb2,
                                          my_ring, prev_own, prev_left);
            }
        }

        // ---- flush rows whose lane-63 value landed by tick T0+KCH-1 ----
        {
            const int hi = min(base_l + KCH - 64, LLEN - 1);
            if (hi - nf == KCH - 1) {             // steady state: exactly KCH rows
                #pragma unroll
                for (int q = 0; q < KCH; ++q) {
                    const int slot = (nf + wskew + lane) & (RINGT - 1);
                    __builtin_nontemporal_store(my_ring[(slot << 6) + lane], outp);
                    outp += NCHAN * 256;
                    ++nf;
                }
            } else {
                for (; nf <= hi; ++nf) {
                    const int slot = (nf + wskew + lane) & (RINGT - 1);
                    __builtin_nontemporal_store(my_ring[(slot << 6) + lane], outp);
                    outp += NCHAN * 256;
                }
            }
        }
        lds_barrier();
    }

    // safety drain (normally empty)
    for (; nf < LLEN; ++nf) {
        const int slot = (nf + wskew + lane) & (RINGT - 1);
        __builtin_nontemporal_store(my_ring[(slot << 6) + lane], outp);
        outp += NCHAN * 256;
    }
}

} // namespace

extern "C" void kernel_launch(void* const* d_in, const int* in_sizes, int n_in,
                              void* d_out, int out_size, void* d_ws, size_t ws_size,
                              hipStream_t stream) {
    (void)in_sizes; (void)n_in; (void)d_ws; (void)ws_size; (void)out_size;
    const float* vin  = (const float*)d_in[0];   // "inputs"
    const float* dtin = (const float*)d_in[1];   // "dt"
    float* out = (float*)d_out;

    (void)hipFuncSetAttribute(reinterpret_cast<const void*>(toeplitz_scan),
                              hipFuncAttributeMaxDynamicSharedMemorySize,
                              (int)LDS_BYTES);

    toeplitz_scan<<<NCHAN, 256, LDS_BYTES, stream>>>(vin, dtin, out);
}